// Round 1
// baseline (61.574 us; speedup 1.0000x reference)
//
#include <hip/hip_runtime.h>

#define IMG_H 4096
#define IMG_W 6144
#define BORDER_VAL 1e20f

// Each thread computes 4 consecutive output pixels (one float4 store).
// out[i,j] = min over p,q in [0,3) of img[i+p-1, j+q-1] - se[p,q],
// with out-of-bounds image pixels = 1e20 (never win the min).
__global__ __launch_bounds__(256) void erode3x3_kernel(
    const float* __restrict__ img,
    const float* __restrict__ se,
    float* __restrict__ out)
{
    const int tx = blockIdx.x * blockDim.x + threadIdx.x;  // column-group index
    const int i  = blockIdx.y;                             // output row
    const int j0 = tx * 4;                                 // first output column
    if (j0 >= IMG_W) return;

    // Structural element: uniform address -> scalar loads, broadcast free.
    const float s00 = se[0], s01 = se[1], s02 = se[2];
    const float s10 = se[3], s11 = se[4], s12 = se[5];
    const float s20 = se[6], s21 = se[7], s22 = se[8];

    // v[p][c]: row i+p-1, columns j0-1 .. j0+4  (c = 0..5)
    float v[3][6];
    #pragma unroll
    for (int p = 0; p < 3; ++p) {
        const int r = i + p - 1;
        if (r < 0 || r >= IMG_H) {
            #pragma unroll
            for (int c = 0; c < 6; ++c) v[p][c] = BORDER_VAL;
        } else {
            const float* __restrict__ row = img + (size_t)r * IMG_W;
            const float4 c4 = *reinterpret_cast<const float4*>(row + j0);
            v[p][1] = c4.x; v[p][2] = c4.y; v[p][3] = c4.z; v[p][4] = c4.w;
            v[p][0] = (j0 > 0)           ? row[j0 - 1] : BORDER_VAL;
            v[p][5] = (j0 + 4 < IMG_W)   ? row[j0 + 4] : BORDER_VAL;
        }
    }

    float o[4];
    #pragma unroll
    for (int k = 0; k < 4; ++k) {
        float m;
        m =            v[0][k + 0] - s00;
        m = fminf(m,   v[0][k + 1] - s01);
        m = fminf(m,   v[0][k + 2] - s02);
        m = fminf(m,   v[1][k + 0] - s10);
        m = fminf(m,   v[1][k + 1] - s11);
        m = fminf(m,   v[1][k + 2] - s12);
        m = fminf(m,   v[2][k + 0] - s20);
        m = fminf(m,   v[2][k + 1] - s21);
        m = fminf(m,   v[2][k + 2] - s22);
        o[k] = m;
    }

    float4* dst = reinterpret_cast<float4*>(out + (size_t)i * IMG_W + j0);
    *dst = make_float4(o[0], o[1], o[2], o[3]);
}

extern "C" void kernel_launch(void* const* d_in, const int* in_sizes, int n_in,
                              void* d_out, int out_size, void* d_ws, size_t ws_size,
                              hipStream_t stream)
{
    const float* img = (const float*)d_in[0];
    const float* se  = (const float*)d_in[1];
    float* out       = (float*)d_out;

    const int groups_per_row = IMG_W / 4;                 // 1536
    dim3 block(256, 1, 1);
    dim3 grid((groups_per_row + 255) / 256, IMG_H, 1);    // (6, 4096)
    erode3x3_kernel<<<grid, block, 0, stream>>>(img, se, out);
}

// Round 2
// 35.092 us; speedup vs baseline: 1.7547x; 1.7547x over previous
//
#include <hip/hip_runtime.h>

#define IMG_H 4096
#define IMG_W 6144
#define BORDER_VAL 1e20f

#define ROWS 8                    // output rows per thread
#define GX 6                      // column groups of 1024 cols (256 thr * 4)
#define GY (IMG_H / ROWS)         // 512 row groups
#define NBLK (GX * GY)            // 3072 blocks
#define NXCD 8
#define BAND (GY / NXCD)          // 64 row-groups per XCD band

// Each thread: 4 consecutive cols x 8 consecutive rows of output.
// Loads 10 input rows (float4 center + 2 edge scalars each) -> in-register
// vertical reuse (amplification 10/8 = 1.25x). XCD-band swizzle puts each
// XCD on a contiguous 512-row band so the 2-row overlap between vertical
// neighbors is an L2 hit on the same XCD.
__global__ __launch_bounds__(256) void erode3x3_kernel(
    const float* __restrict__ img,
    const float* __restrict__ se,
    float* __restrict__ out)
{
    // HW round-robins blocks over 8 XCDs: xcd = blockIdx.x % 8 (heuristic,
    // affects only locality). Give XCD k the row-band [k*BAND, (k+1)*BAND).
    const int v    = blockIdx.x;
    const int xcd  = v & 7;
    const int slot = v >> 3;                 // 0..NBLK/8-1
    const int gy   = xcd * BAND + slot / GX; // row group
    const int gx   = slot - (slot / GX) * GX;

    const int j0 = (gx * 256 + (int)threadIdx.x) * 4;  // first output column
    const int r0 = gy * ROWS;                          // first output row

    const float s00 = se[0], s01 = se[1], s02 = se[2];
    const float s10 = se[3], s11 = se[4], s12 = se[5];
    const float s20 = se[6], s21 = se[7], s22 = se[8];

    // vbuf[p][c]: input row r0 + p - 1, columns j0-1 .. j0+4.
    float vbuf[ROWS + 2][6];
    #pragma unroll
    for (int p = 0; p < ROWS + 2; ++p) {
        const int r = r0 + p - 1;
        if (r < 0 || r >= IMG_H) {           // wave-uniform branch
            #pragma unroll
            for (int c = 0; c < 6; ++c) vbuf[p][c] = BORDER_VAL;
        } else {
            const float* __restrict__ row = img + (size_t)r * IMG_W;
            const float4 c4 = *reinterpret_cast<const float4*>(row + j0);
            vbuf[p][1] = c4.x; vbuf[p][2] = c4.y;
            vbuf[p][3] = c4.z; vbuf[p][4] = c4.w;
            vbuf[p][0] = (j0 > 0)         ? row[j0 - 1] : BORDER_VAL;
            vbuf[p][5] = (j0 + 4 < IMG_W) ? row[j0 + 4] : BORDER_VAL;
        }
    }

    #pragma unroll
    for (int rr = 0; rr < ROWS; ++rr) {
        float o[4];
        #pragma unroll
        for (int k = 0; k < 4; ++k) {
            float m;
            m =          vbuf[rr + 0][k + 0] - s00;
            m = fminf(m, vbuf[rr + 0][k + 1] - s01);
            m = fminf(m, vbuf[rr + 0][k + 2] - s02);
            m = fminf(m, vbuf[rr + 1][k + 0] - s10);
            m = fminf(m, vbuf[rr + 1][k + 1] - s11);
            m = fminf(m, vbuf[rr + 1][k + 2] - s12);
            m = fminf(m, vbuf[rr + 2][k + 0] - s20);
            m = fminf(m, vbuf[rr + 2][k + 1] - s21);
            m = fminf(m, vbuf[rr + 2][k + 2] - s22);
            o[k] = m;
        }
        float4* dst = reinterpret_cast<float4*>(out + (size_t)(r0 + rr) * IMG_W + j0);
        *dst = make_float4(o[0], o[1], o[2], o[3]);
    }
}

extern "C" void kernel_launch(void* const* d_in, const int* in_sizes, int n_in,
                              void* d_out, int out_size, void* d_ws, size_t ws_size,
                              hipStream_t stream)
{
    const float* img = (const float*)d_in[0];
    const float* se  = (const float*)d_in[1];
    float* out       = (float*)d_out;

    dim3 block(256, 1, 1);
    dim3 grid(NBLK, 1, 1);
    erode3x3_kernel<<<grid, block, 0, stream>>>(img, se, out);
}